// Round 4
// baseline (202.116 us; speedup 1.0000x reference)
//
#include <hip/hip_runtime.h>

// Erosion = 18x18 separable min-filter, SAME padding (lo=8, hi=9) with +inf,
// applied to x*0.5+0.5. Affine is monotone & exact, so min-filter raw x and
// apply *0.5+0.5 once at the end (bitwise identical).
//
// R4: ALL memory traffic at 16 B/lane (theory: scalar dword streams cap at
// ~3 TB/s per-lane-request rate; float4 reaches ~6.3 TB/s).
//  - P1 vertical: each unit owns a float4-column x 8 output rows. 25 float4
//    global loads (lane-contiguous), van Herk suffix/prefix scan (low VGPR),
//    b128 writes to LDS B4[64][38] (contiguous lanes -> conflict-free).
//  - P2 horizontal: 6 b128 row-reads per 4 outputs (lanes span 32 col-groups
//    -> uniform banks, conflict-free), min-tree, affine, float4 stores
//    (32-lane contiguous 512 B runs).
// Tile 128(w) x 64(h), 256 threads, one barrier. LDS 38.9 KB -> 4 blocks/CU.

#define IMG 512

__device__ __forceinline__ float4 f4min(float4 a, float4 b) {
    return make_float4(fminf(a.x, b.x), fminf(a.y, b.y),
                       fminf(a.z, b.z), fminf(a.w, b.w));
}

__global__ __launch_bounds__(256, 4)
void erode_fused_22187801051678(const float* __restrict__ in,
                                float* __restrict__ out) {
    __shared__ float4 B4[64][38];  // [row][f4col]; 37 used, stride 38 (pad)

    const int tid = threadIdx.x;
    const int w0 = blockIdx.x * 128;
    const int h0 = blockIdx.y * 64;
    const size_t plane = (size_t)blockIdx.z * (size_t)(IMG * IMG);

    const float4 VINF = make_float4(__builtin_inff(), __builtin_inff(),
                                    __builtin_inff(), __builtin_inff());

    // ---- phase 1: vertical 18-tap min (van Herk), f4-column units.
    // 296 units = 37 f4cols x 8 segs (8 out rows each). Seg loads 25 rows.
    for (int u = tid; u < 296; u += 256) {
        const int c = u % 37;
        const int s = u / 37;
        const int cb = w0 - 8 + 4 * c;            // 4-aligned column base
        const bool wok = (unsigned)cb < (unsigned)IMG;  // whole f4 in or out
        const int rbase = h0 + 8 * s - 8;         // input row of x[0]
        const float* bp = in + plane + cb;

#define LD(i) ((wok && (unsigned)(rbase + (i)) < (unsigned)IMG)               \
                   ? *reinterpret_cast<const float4*>(                        \
                         bp + (size_t)(rbase + (i)) * IMG)                    \
                   : VINF)

        // suffix scan over x[0..17]: S[j] = min(x[j..17]) for j=0..7
        float4 S[8];
        float4 rs = LD(17);
#pragma unroll
        for (int i = 16; i >= 0; --i) {
            rs = f4min(rs, LD(i));
            if (i < 8) S[i] = rs;   // static index under full unroll
        }
        // prefix scan over x[18..24]; out[j] = min(S[j], min(x[18..j+17]))
        const int rb = 8 * s;
        B4[rb + 0][c] = S[0];
        float4 rp = LD(18);
        B4[rb + 1][c] = f4min(S[1], rp);
#pragma unroll
        for (int i = 19; i <= 24; ++i) {
            rp = f4min(rp, LD(i));
            B4[rb + (i - 17)][c] = f4min(S[i - 17], rp);
        }
#undef LD
    }
    __syncthreads();

    // ---- phase 2: horizontal 18-tap min + affine + f4 stores.
    // 2048 units = 64 rows x 32 f4-outcols; 8 sweeps of 256.
    const int gq = tid & 31;   // f4 output-column group (cols w0+4gq..+3)
    const int r0 = tid >> 5;   // row low bits
#pragma unroll
    for (int sw = 0; sw < 8; ++sw) {
        const int r = r0 + 8 * sw;
        float z[24];  // words 4gq .. 4gq+23 of row r (need ..+20)
#pragma unroll
        for (int k = 0; k < 6; ++k) {
            const float4 v = B4[r][gq + k];
            z[4 * k + 0] = v.x; z[4 * k + 1] = v.y;
            z[4 * k + 2] = v.z; z[4 * k + 3] = v.w;
        }
        // o[t] = min(z[t..t+17]); shared core = min(z[3..17])
        const float a0 = fminf(z[3], z[4]);
        const float a1 = fminf(z[5], z[6]);
        const float a2 = fminf(z[7], z[8]);
        const float a3 = fminf(z[9], z[10]);
        const float a4 = fminf(z[11], z[12]);
        const float a5 = fminf(z[13], z[14]);
        const float a6 = fminf(z[15], z[16]);
        const float b0 = fminf(a0, a1), b1 = fminf(a2, a3);
        const float b2 = fminf(a4, a5), b3 = fminf(a6, z[17]);
        const float core = fminf(fminf(b0, b1), fminf(b2, b3));
        const float o0 = fminf(fminf(z[0], z[1]), fminf(z[2], core));
        const float o1 = fminf(fminf(z[1], z[2]), fminf(core, z[18]));
        const float o2 = fminf(fminf(z[2], core), fminf(z[18], z[19]));
        const float o3 = fminf(fminf(core, z[18]), fminf(z[19], z[20]));
        const float4 res = make_float4(o0 * 0.5f + 0.5f, o1 * 0.5f + 0.5f,
                                       o2 * 0.5f + 0.5f, o3 * 0.5f + 0.5f);
        *reinterpret_cast<float4*>(
            out + plane + (size_t)(h0 + r) * IMG + (w0 + 4 * gq)) = res;
    }
}

extern "C" void kernel_launch(void* const* d_in, const int* in_sizes, int n_in,
                              void* d_out, int out_size, void* d_ws, size_t ws_size,
                              hipStream_t stream) {
    const float* x = (const float*)d_in[0];
    float* out = (float*)d_out;
    const int planes = in_sizes[0] / (IMG * IMG);  // 96 for (32,3,512,512)
    dim3 grid(IMG / 128, IMG / 64, planes);
    erode_fused_22187801051678<<<grid, dim3(256), 0, stream>>>(x, out);
}

// Round 5
// 188.465 us; speedup vs baseline: 1.0724x; 1.0724x over previous
//
#include <hip/hip_runtime.h>

// Erosion = 18x18 separable min-filter, SAME padding (lo=8, hi=9) with +inf,
// applied to x*0.5+0.5. Affine is monotone & exact: filter raw x, apply
// *0.5+0.5 once at the end (bitwise identical).
//
// R5 = R4 + forced memory-level parallelism. Diagnosis: compiler interleaves
// each global load with its consuming fminf (VGPR_Count 24..52 despite large
// declared arrays) -> ~2 outstanding loads/wave -> latency-bound ~3 TB/s
// regardless of occupancy/vector width. Fix: issue ALL 25 float4 loads with
// clamped (always-valid) addresses, sched_barrier(0), THEN mask + scan.
// __launch_bounds__(256,3): VGPR cap ~170, fits X[25]+S[8], no spill.

#define IMG 512

__device__ __forceinline__ float4 f4min(float4 a, float4 b) {
    return make_float4(fminf(a.x, b.x), fminf(a.y, b.y),
                       fminf(a.z, b.z), fminf(a.w, b.w));
}

__global__ __launch_bounds__(256, 3)
void erode_fused_22187801051678(const float* __restrict__ in,
                                float* __restrict__ out) {
    __shared__ float4 B4[64][38];  // [row][f4col]; 37 used, +1 pad

    const int tid = threadIdx.x;
    const int w0 = blockIdx.x * 128;
    const int h0 = blockIdx.y * 64;
    const size_t plane = (size_t)blockIdx.z * (size_t)(IMG * IMG);

    const float4 VINF = make_float4(__builtin_inff(), __builtin_inff(),
                                    __builtin_inff(), __builtin_inff());

    // ---- phase 1: vertical 18-tap min (van Herk), f4-column units.
    // 296 units = 37 f4cols x 8 segs (8 output rows each; 25 input rows).
    for (int u = tid; u < 296; u += 256) {
        const int c = u % 37;
        const int s = u / 37;
        const int cb = w0 - 8 + 4 * c;                  // 4-aligned col base
        const bool wok = (unsigned)cb < (unsigned)IMG;  // whole f4 in or out
        const int cbc = min(max(cb, 0), IMG - 4);       // clamped (valid) base
        const int rbase = h0 + 8 * s - 8;               // input row of X[0]
        const float* bp = in + plane + cbc;

        // Batch-issue all 25 loads, addresses clamped -> unconditional.
        float4 X[25];
#pragma unroll
        for (int i = 0; i < 25; ++i) {
            const int ghc = min(max(rbase + i, 0), IMG - 1);
            X[i] = *reinterpret_cast<const float4*>(bp + (size_t)ghc * IMG);
        }
        __builtin_amdgcn_sched_barrier(0);  // loads stay batched above

        // Mask out-of-bounds with +inf (cndmask, no branches).
#pragma unroll
        for (int i = 0; i < 25; ++i) {
            const int gh = rbase + i;
            if (!(wok && (unsigned)gh < (unsigned)IMG)) X[i] = VINF;
        }

        // van Herk: suffix scan S[j]=min(X[j..17]), then prefix extension.
        float4 S[8];
        float4 rs = X[17];
#pragma unroll
        for (int i = 16; i >= 0; --i) {
            rs = f4min(rs, X[i]);
            if (i < 8) S[i] = rs;  // static under full unroll
        }
        const int rb = 8 * s;
        B4[rb + 0][c] = S[0];
        float4 rp = X[18];
        B4[rb + 1][c] = f4min(S[1], rp);
#pragma unroll
        for (int i = 19; i <= 24; ++i) {
            rp = f4min(rp, X[i]);
            B4[rb + (i - 17)][c] = f4min(S[i - 17], rp);
        }
    }
    __syncthreads();

    // ---- phase 2: horizontal 18-tap min + affine + f4 stores.
    // 2048 units = 64 rows x 32 f4-outcols; 8 sweeps of 256 threads.
    const int gq = tid & 31;
    const int r0 = tid >> 5;
#pragma unroll
    for (int sw = 0; sw < 8; ++sw) {
        const int r = r0 + 8 * sw;
        float z[24];
#pragma unroll
        for (int k = 0; k < 6; ++k) {
            const float4 v = B4[r][gq + k];
            z[4 * k + 0] = v.x; z[4 * k + 1] = v.y;
            z[4 * k + 2] = v.z; z[4 * k + 3] = v.w;
        }
        const float a0 = fminf(z[3], z[4]);
        const float a1 = fminf(z[5], z[6]);
        const float a2 = fminf(z[7], z[8]);
        const float a3 = fminf(z[9], z[10]);
        const float a4 = fminf(z[11], z[12]);
        const float a5 = fminf(z[13], z[14]);
        const float a6 = fminf(z[15], z[16]);
        const float b0 = fminf(a0, a1), b1 = fminf(a2, a3);
        const float b2 = fminf(a4, a5), b3 = fminf(a6, z[17]);
        const float core = fminf(fminf(b0, b1), fminf(b2, b3));
        const float o0 = fminf(fminf(z[0], z[1]), fminf(z[2], core));
        const float o1 = fminf(fminf(z[1], z[2]), fminf(core, z[18]));
        const float o2 = fminf(fminf(z[2], core), fminf(z[18], z[19]));
        const float o3 = fminf(fminf(core, z[18]), fminf(z[19], z[20]));
        const float4 res = make_float4(o0 * 0.5f + 0.5f, o1 * 0.5f + 0.5f,
                                       o2 * 0.5f + 0.5f, o3 * 0.5f + 0.5f);
        *reinterpret_cast<float4*>(
            out + plane + (size_t)(h0 + r) * IMG + (w0 + 4 * gq)) = res;
    }
}

extern "C" void kernel_launch(void* const* d_in, const int* in_sizes, int n_in,
                              void* d_out, int out_size, void* d_ws, size_t ws_size,
                              hipStream_t stream) {
    const float* x = (const float*)d_in[0];
    float* out = (float*)d_out;
    const int planes = in_sizes[0] / (IMG * IMG);  // 96 for (32,3,512,512)
    dim3 grid(IMG / 128, IMG / 64, planes);
    erode_fused_22187801051678<<<grid, dim3(256), 0, stream>>>(x, out);
}